// Round 18
// baseline (4258.575 us; speedup 1.0000x reference)
//
#include <hip/hip_runtime.h>
#include <hip/hip_bf16.h>
#include <math.h>

#define SLEN 2048
#define DDIM 512
#define BNUM 8
#define MTOT (BNUM * SLEN)   // 16384

typedef float f32x4 __attribute__((ext_vector_type(4)));
typedef short s16x8 __attribute__((ext_vector_type(8)));   // 8 bf16 (4 VGPRs)

// fp32 -> bf16 (RNE) as raw ushort
__device__ __forceinline__ unsigned short f2bf(float f) {
    unsigned u = __float_as_uint(f);
    u += 0x7FFFu + ((u >> 16) & 1u);
    return (unsigned short)(u >> 16);
}

// ---------------------------------------------------------------------------
// Device-scope (sc1) 8-byte access. Proven: sc0 = SE scope (r8); atomics as
// poll = L2 dirtying disaster (r13); issue+waitcnt must live in ONE asm
// block (r12); gate loads must NOT sit between poll-exit and publish (r17).
// ---------------------------------------------------------------------------
__device__ __forceinline__ void st_u64_sc1(uint2* p, uint2 v) {
    asm volatile("global_store_dwordx2 %0, %1, off sc1"
                 :: "v"(p), "v"(v) : "memory");
}
__device__ __forceinline__ uint2 ld_u64_sc1(const uint2* p) {
    uint2 v;
    asm volatile("global_load_dwordx2 %0, %1, off sc1\n\ts_waitcnt vmcnt(0)"
                 : "=v"(v) : "v"(p) : "memory");
    return v;
}

// ---------------------------------------------------------------------------
// Pipelined tag poll, ENTIRELY inside one asm block (r12 lesson): 4 rotating
// 8B sc1 loads in fixed clobbered regs v[10:17]; FIFO vmcnt(3) waits make
// each check read completed data; s_sleep 2 spaces samples ~160cy apart
// (serial polling samples once per ~600cy RT). Exit when ALL lanes match
// (v_cmp + s_andn2 vs exec). Tags are monotonic within a slot+parity, so a
// buffer loaded before arrival can only flip old->want once — rechecks are
// safe. Guard s82 turns protocol bugs into wrong answers, never hangs.
// ---------------------------------------------------------------------------
__device__ __forceinline__ float poll_pipelined(const uint2* p, unsigned want) {
    float val;
    asm volatile(
        "s_mov_b32 s82, 0\n\t"
        "global_load_dwordx2 v[10:11], %[p], off sc1\n\t"
        "s_sleep 1\n\t"
        "global_load_dwordx2 v[12:13], %[p], off sc1\n\t"
        "s_sleep 1\n\t"
        "global_load_dwordx2 v[14:15], %[p], off sc1\n\t"
        "s_sleep 1\n\t"
        "global_load_dwordx2 v[16:17], %[p], off sc1\n\t"
        "Lpoll%=:\n\t"
        "s_add_u32 s82, s82, 1\n\t"
        "s_cmp_ge_u32 s82, 0x10000\n\t"
        "s_cbranch_scc1 Ld0%=\n\t"
        "s_waitcnt vmcnt(3)\n\t"
        "v_cmp_eq_u32 vcc, %[want], v11\n\t"
        "s_andn2_b64 s[80:81], exec, vcc\n\t"
        "s_cbranch_scc0 Ld0%=\n\t"
        "global_load_dwordx2 v[10:11], %[p], off sc1\n\t"
        "s_sleep 2\n\t"
        "s_waitcnt vmcnt(3)\n\t"
        "v_cmp_eq_u32 vcc, %[want], v13\n\t"
        "s_andn2_b64 s[80:81], exec, vcc\n\t"
        "s_cbranch_scc0 Ld1%=\n\t"
        "global_load_dwordx2 v[12:13], %[p], off sc1\n\t"
        "s_sleep 2\n\t"
        "s_waitcnt vmcnt(3)\n\t"
        "v_cmp_eq_u32 vcc, %[want], v15\n\t"
        "s_andn2_b64 s[80:81], exec, vcc\n\t"
        "s_cbranch_scc0 Ld2%=\n\t"
        "global_load_dwordx2 v[14:15], %[p], off sc1\n\t"
        "s_sleep 2\n\t"
        "s_waitcnt vmcnt(3)\n\t"
        "v_cmp_eq_u32 vcc, %[want], v17\n\t"
        "s_andn2_b64 s[80:81], exec, vcc\n\t"
        "s_cbranch_scc0 Ld3%=\n\t"
        "global_load_dwordx2 v[16:17], %[p], off sc1\n\t"
        "s_sleep 2\n\t"
        "s_branch Lpoll%=\n\t"
        "Ld0%=:\n\t"
        "v_mov_b32 %[val], v10\n\t"
        "s_branch Lend%=\n\t"
        "Ld1%=:\n\t"
        "v_mov_b32 %[val], v12\n\t"
        "s_branch Lend%=\n\t"
        "Ld2%=:\n\t"
        "v_mov_b32 %[val], v14\n\t"
        "s_branch Lend%=\n\t"
        "Ld3%=:\n\t"
        "v_mov_b32 %[val], v16\n\t"
        "Lend%=:\n\t"
        "s_waitcnt vmcnt(0)"
        : [val] "=v"(val)
        : [p] "v"(p), [want] "v"(want)
        : "memory", "vcc",
          "v10","v11","v12","v13","v14","v15","v16","v17",
          "s80","s81","s82");
    return val;
}

// ---------------------------------------------------------------------------
// Kernel 0: clear tag buffer through the SAME sc1 path the scan uses.
// ---------------------------------------------------------------------------
__global__ __launch_bounds__(512) void clear_tags_kernel(uint2* stateTag)
{
    int i = blockIdx.x * 512 + threadIdx.x;
    uint2 z; z.x = 0u; z.y = 0u;
    st_u64_sc1(&stateTag[i], z);
}

// ---------------------------------------------------------------------------
// Kernel A: fused precompute GEMM via bf16 MFMA (round-10, proven).
// ---------------------------------------------------------------------------
__global__ __launch_bounds__(256) void precompute_kernel(
    const float* __restrict__ x,
    const float* __restrict__ Wu, const float* __restrict__ bu,
    const float* __restrict__ Wa, const float* __restrict__ ba,
    const float* __restrict__ Wc, const float* __restrict__ bc,
    const float* __restrict__ Wg, const float* __restrict__ bg,
    float* __restrict__ gbuf, float* __restrict__ cosb,
    float* __restrict__ sinb, float* __restrict__ cdbuf,
    float* __restrict__ ogout)
{
    __shared__ unsigned short As[128 * 40];
    __shared__ unsigned short Bs[128 * 40];

    const int bn = blockIdx.x * 128;      // 0..1791 in steps of 128
    const int bm = blockIdx.y * 128;      // 0..16383

    const float* W; const float* bias; int mode; int dcol;
    if (bn < 512)       { W = Wu; bias = bu; mode = 0; dcol = bn; }
    else if (bn < 768)  { W = Wa; bias = ba; mode = 1; dcol = bn - 512; }
    else if (bn < 1280) { W = Wc; bias = bc; mode = 2; dcol = bn - 768; }
    else                { W = Wg; bias = bg; mode = 3; dcol = bn - 1280; }

    const int tid  = threadIdx.x;
    const int lane = tid & 63, wv = tid >> 6;
    const int wm = wv >> 1, wn = wv & 1;
    const int lr  = lane & 15;
    const int lkb = (lane >> 4) * 8;      // ushort offset of the 8-k group

    f32x4 acc[4][4];
    #pragma unroll
    for (int i = 0; i < 4; ++i)
        #pragma unroll
        for (int j = 0; j < 4; ++j)
            acc[i][j] = (f32x4){0.f, 0.f, 0.f, 0.f};

    const int r = tid >> 1, h = tid & 1;  // staging: row, k-half
    const float* aSrc = x + (size_t)(bm + r) * DDIM + h * 16;
    const float* bSrc = W + (size_t)(dcol + r) * DDIM + h * 16;
    unsigned short* aDst = &As[r * 40 + h * 16];
    unsigned short* bDst = &Bs[r * 40 + h * 16];

    for (int kt = 0; kt < 16; ++kt) {
        {
            float4 fa0 = *(const float4*)(aSrc + 0);
            float4 fa1 = *(const float4*)(aSrc + 4);
            float4 fa2 = *(const float4*)(aSrc + 8);
            float4 fa3 = *(const float4*)(aSrc + 12);
            union { unsigned short u[8]; s16x8 v; } pa0, pa1;
            pa0.u[0]=f2bf(fa0.x); pa0.u[1]=f2bf(fa0.y); pa0.u[2]=f2bf(fa0.z); pa0.u[3]=f2bf(fa0.w);
            pa0.u[4]=f2bf(fa1.x); pa0.u[5]=f2bf(fa1.y); pa0.u[6]=f2bf(fa1.z); pa0.u[7]=f2bf(fa1.w);
            pa1.u[0]=f2bf(fa2.x); pa1.u[1]=f2bf(fa2.y); pa1.u[2]=f2bf(fa2.z); pa1.u[3]=f2bf(fa2.w);
            pa1.u[4]=f2bf(fa3.x); pa1.u[5]=f2bf(fa3.y); pa1.u[6]=f2bf(fa3.z); pa1.u[7]=f2bf(fa3.w);
            *(s16x8*)(aDst + 0) = pa0.v;
            *(s16x8*)(aDst + 8) = pa1.v;

            float4 fb0 = *(const float4*)(bSrc + 0);
            float4 fb1 = *(const float4*)(bSrc + 4);
            float4 fb2 = *(const float4*)(bSrc + 8);
            float4 fb3 = *(const float4*)(bSrc + 12);
            union { unsigned short u[8]; s16x8 v; } pb0, pb1;
            pb0.u[0]=f2bf(fb0.x); pb0.u[1]=f2bf(fb0.y); pb0.u[2]=f2bf(fb0.z); pb0.u[3]=f2bf(fb0.w);
            pb0.u[4]=f2bf(fb1.x); pb0.u[5]=f2bf(fb1.y); pb0.u[6]=f2bf(fb1.z); pb0.u[7]=f2bf(fb1.w);
            pb1.u[0]=f2bf(fb2.x); pb1.u[1]=f2bf(fb2.y); pb1.u[2]=f2bf(fb2.z); pb1.u[3]=f2bf(fb2.w);
            pb1.u[4]=f2bf(fb3.x); pb1.u[5]=f2bf(fb3.y); pb1.u[6]=f2bf(fb3.z); pb1.u[7]=f2bf(fb3.w);
            *(s16x8*)(bDst + 0) = pb0.v;
            *(s16x8*)(bDst + 8) = pb1.v;

            aSrc += 32; bSrc += 32;
        }
        __syncthreads();

        s16x8 af[4], bf[4];
        #pragma unroll
        for (int i = 0; i < 4; ++i)
            af[i] = *(const s16x8*)&As[(wm * 64 + i * 16 + lr) * 40 + lkb];
        #pragma unroll
        for (int j = 0; j < 4; ++j)
            bf[j] = *(const s16x8*)&Bs[(wn * 64 + j * 16 + lr) * 40 + lkb];
        #pragma unroll
        for (int i = 0; i < 4; ++i)
            #pragma unroll
            for (int j = 0; j < 4; ++j)
                acc[i][j] = __builtin_amdgcn_mfma_f32_16x16x32_bf16(
                    af[i], bf[j], acc[i][j], 0, 0, 0);
        __syncthreads();
    }

    // ---- epilogue: bias + activation ----
    const int orow = (lane >> 4) * 4;
    #pragma unroll
    for (int i = 0; i < 4; ++i) {
        #pragma unroll
        for (int j = 0; j < 4; ++j) {
            #pragma unroll
            for (int v = 0; v < 4; ++v) {
                int m  = bm + wm * 64 + i * 16 + orow + v;
                int nc = dcol + wn * 64 + j * 16 + lr;
                float val = acc[i][j][v] + bias[nc];
                if (mode == 0) {
                    gbuf[(size_t)m * 512 + nc] = 1.f / (1.f + expf(-val));
                } else if (mode == 1) {
                    cosb[(size_t)m * 256 + nc] = cosf(val);
                    sinb[(size_t)m * 256 + nc] = sinf(val);
                } else if (mode == 2) {
                    cdbuf[(size_t)m * 512 + nc] = tanhf(val);
                } else {
                    ogout[(size_t)m * 512 + nc] = 1.f / (1.f + expf(-val));
                }
            }
        }
    }
}

// 64-MAC dot of register weight slice P0..P15 with 64 contiguous LDS floats.
// (P##N).x parens required: `P##2.y` pastes against pp-number `2.y` (r14).
#define DOT64(P, ST, OUT) { \
    f32x4 sv_; float q0_=0.f,q1_=0.f,q2_=0.f,q3_=0.f; \
    sv_=*(const f32x4*)((ST)+ 0); q0_=fmaf((P##0).x,sv_.x,q0_); q1_=fmaf((P##0).y,sv_.y,q1_); q2_=fmaf((P##0).z,sv_.z,q2_); q3_=fmaf((P##0).w,sv_.w,q3_); \
    sv_=*(const f32x4*)((ST)+ 4); q0_=fmaf((P##1).x,sv_.x,q0_); q1_=fmaf((P##1).y,sv_.y,q1_); q2_=fmaf((P##1).z,sv_.z,q2_); q3_=fmaf((P##1).w,sv_.w,q3_); \
    sv_=*(const f32x4*)((ST)+ 8); q0_=fmaf((P##2).x,sv_.x,q0_); q1_=fmaf((P##2).y,sv_.y,q1_); q2_=fmaf((P##2).z,sv_.z,q2_); q3_=fmaf((P##2).w,sv_.w,q3_); \
    sv_=*(const f32x4*)((ST)+12); q0_=fmaf((P##3).x,sv_.x,q0_); q1_=fmaf((P##3).y,sv_.y,q1_); q2_=fmaf((P##3).z,sv_.z,q2_); q3_=fmaf((P##3).w,sv_.w,q3_); \
    sv_=*(const f32x4*)((ST)+16); q0_=fmaf((P##4).x,sv_.x,q0_); q1_=fmaf((P##4).y,sv_.y,q1_); q2_=fmaf((P##4).z,sv_.z,q2_); q3_=fmaf((P##4).w,sv_.w,q3_); \
    sv_=*(const f32x4*)((ST)+20); q0_=fmaf((P##5).x,sv_.x,q0_); q1_=fmaf((P##5).y,sv_.y,q1_); q2_=fmaf((P##5).z,sv_.z,q2_); q3_=fmaf((P##5).w,sv_.w,q3_); \
    sv_=*(const f32x4*)((ST)+24); q0_=fmaf((P##6).x,sv_.x,q0_); q1_=fmaf((P##6).y,sv_.y,q1_); q2_=fmaf((P##6).z,sv_.z,q2_); q3_=fmaf((P##6).w,sv_.w,q3_); \
    sv_=*(const f32x4*)((ST)+28); q0_=fmaf((P##7).x,sv_.x,q0_); q1_=fmaf((P##7).y,sv_.y,q1_); q2_=fmaf((P##7).z,sv_.z,q2_); q3_=fmaf((P##7).w,sv_.w,q3_); \
    sv_=*(const f32x4*)((ST)+32); q0_=fmaf((P##8).x,sv_.x,q0_); q1_=fmaf((P##8).y,sv_.y,q1_); q2_=fmaf((P##8).z,sv_.z,q2_); q3_=fmaf((P##8).w,sv_.w,q3_); \
    sv_=*(const f32x4*)((ST)+36); q0_=fmaf((P##9).x,sv_.x,q0_); q1_=fmaf((P##9).y,sv_.y,q1_); q2_=fmaf((P##9).z,sv_.z,q2_); q3_=fmaf((P##9).w,sv_.w,q3_); \
    sv_=*(const f32x4*)((ST)+40); q0_=fmaf((P##10).x,sv_.x,q0_); q1_=fmaf((P##10).y,sv_.y,q1_); q2_=fmaf((P##10).z,sv_.z,q2_); q3_=fmaf((P##10).w,sv_.w,q3_); \
    sv_=*(const f32x4*)((ST)+44); q0_=fmaf((P##11).x,sv_.x,q0_); q1_=fmaf((P##11).y,sv_.y,q1_); q2_=fmaf((P##11).z,sv_.z,q2_); q3_=fmaf((P##11).w,sv_.w,q3_); \
    sv_=*(const f32x4*)((ST)+48); q0_=fmaf((P##12).x,sv_.x,q0_); q1_=fmaf((P##12).y,sv_.y,q1_); q2_=fmaf((P##12).z,sv_.z,q2_); q3_=fmaf((P##12).w,sv_.w,q3_); \
    sv_=*(const f32x4*)((ST)+52); q0_=fmaf((P##13).x,sv_.x,q0_); q1_=fmaf((P##13).y,sv_.y,q1_); q2_=fmaf((P##13).z,sv_.z,q2_); q3_=fmaf((P##13).w,sv_.w,q3_); \
    sv_=*(const f32x4*)((ST)+56); q0_=fmaf((P##14).x,sv_.x,q0_); q1_=fmaf((P##14).y,sv_.y,q1_); q2_=fmaf((P##14).z,sv_.z,q2_); q3_=fmaf((P##14).w,sv_.w,q3_); \
    sv_=*(const f32x4*)((ST)+60); q0_=fmaf((P##15).x,sv_.x,q0_); q1_=fmaf((P##15).y,sv_.y,q1_); q2_=fmaf((P##15).z,sv_.z,q2_); q3_=fmaf((P##15).w,sv_.w,q3_); \
    OUT = (q0_+q1_)+(q2_+q3_); }

#define LOADW(P, SRC) \
    f32x4 P##0=*(const f32x4*)((SRC)+ 0), P##1=*(const f32x4*)((SRC)+ 4), \
          P##2=*(const f32x4*)((SRC)+ 8), P##3=*(const f32x4*)((SRC)+12), \
          P##4=*(const f32x4*)((SRC)+16), P##5=*(const f32x4*)((SRC)+20), \
          P##6=*(const f32x4*)((SRC)+24), P##7=*(const f32x4*)((SRC)+28), \
          P##8=*(const f32x4*)((SRC)+32), P##9=*(const f32x4*)((SRC)+36), \
          P##10=*(const f32x4*)((SRC)+40), P##11=*(const f32x4*)((SRC)+44), \
          P##12=*(const f32x4*)((SRC)+48), P##13=*(const f32x4*)((SRC)+52), \
          P##14=*(const f32x4*)((SRC)+56), P##15=*(const f32x4*)((SRC)+60); \
    asm volatile("" : "+v"(P##0), "+v"(P##1), "+v"(P##2),  "+v"(P##3), \
                      "+v"(P##4), "+v"(P##5), "+v"(P##6),  "+v"(P##7), \
                      "+v"(P##8), "+v"(P##9), "+v"(P##10), "+v"(P##11), \
                      "+v"(P##12), "+v"(P##13), "+v"(P##14), "+v"(P##15));

// ---------------------------------------------------------------------------
// Kernel B: sequential scan = round-11 proven structure (best measured,
// 1.29us/step) + (1) gate prefetch at sub-step TOP via 2x-unrolled loop
// with static gA/gB register sets (~500cy head start before the poll's
// drain; consumption unchanged: next sub-step's rotate), and (2) the
// single-asm pipelined poll. 64 WGs x 512 thr: b = wg&7, oct = wg>>3 owns
// rows [oct*64, +64). Lane (wave w, lane l): row o = oct*64 + w*8 + (l>>3),
// k-segment (l&7)*64 (64 f32 weights in VGPR/AGPR). Reduce = shfl_xor
// (1,2,4) + shfl_xor(8). kseg==0 lanes publish; wave w != oct polls
// segment w. sc1 tagged parity double buffer; ONE barrier per step.
// ---------------------------------------------------------------------------
__global__ __launch_bounds__(512, 2) void scan_kernel(
    const float* __restrict__ Wt, const float* __restrict__ bt,
    const float* __restrict__ gbuf, const float* __restrict__ cosb,
    const float* __restrict__ sinb, const float* __restrict__ cdbuf,
    float* __restrict__ states, uint2* stateTag,
    float* __restrict__ finalOut)
{
    const int wg = blockIdx.x;
    const int b = wg & 7, oct = wg >> 3;
    const int tid = threadIdx.x;
    const int w = tid >> 6;
    const int l = tid & 63;
    const int kseg = l & 7;
    const int rl = l >> 3;
    const int o = oct * 64 + w * 8 + rl;   // row this lane computes
    const int e = w * 64 + l;              // element wave w polls (w != oct)
    const bool isPub = (kseg == 0);

    __shared__ float stt[2][8][68];        // [parity][segment][element]

    LOADW(wt, Wt + (size_t)o * DDIM + kseg * 64)
    const float btv = bt[o];

    const float* pg  = gbuf  + (size_t)b * SLEN * 512;
    const float* pcd = cdbuf + (size_t)b * SLEN * 512;
    const float* pc  = cosb  + (size_t)b * SLEN * 256;
    const float* psn = sinb  + (size_t)b * SLEN * 256;
    float* stb = states + (size_t)b * SLEN * 512;

    stt[0][w][l] = 0.f;    // S_0 = 0

    // static double-buffered gate registers; prologue loads set A (step 0)
    float gA = 0.f, cdA = 0.f, cA = 0.f, snA = 0.f;
    float gB = 0.f, cdB = 0.f, cB = 0.f, snB = 0.f;
    if (isPub) {
        gA  = pg [o];
        cdA = pcd[o];
        cA  = pc [o >> 1];
        snA = psn[o >> 1];
    }
    __syncthreads();

    for (int s = 0; s < SLEN; s += 2) {
        // ============ even sub-step: step s, par 0 -> fills stt[1] =========
        {
            const unsigned want = (unsigned)(s + 1);
            // gate prefetch for step s+1 at TOP (consumed next sub-step)
            if (isPub) {
                size_t sp1 = s + 1;
                gB  = pg [sp1 * 512 + o];
                cdB = pcd[sp1 * 512 + o];
                cB  = pc [sp1 * 256 + (o >> 1)];
                snB = psn[sp1 * 256 + (o >> 1)];
            }
            float t;
            DOT64(wt, &stt[0][kseg][0], t)
            t += __shfl_xor(t, 1);
            t += __shfl_xor(t, 2);
            t += __shfl_xor(t, 4);
            t += btv;
            float tp = __shfl_xor(t, 8);

            if (isPub) {
                float rot = (rl & 1) ? fmaf(tp, snA, t * cA)
                                     : fmaf(t, cA, -(tp * snA));
                float nxt = fmaf(gA, rot, (1.f - gA) * cdA);
                uint2 u; u.x = __float_as_uint(nxt); u.y = want;   // s+1<=2047
                st_u64_sc1(&stateTag[((size_t)1 * BNUM + b) * 512 + o], u);
                stt[1][oct][w * 8 + rl] = nxt;
                stb[(size_t)s * 512 + o] = nxt;
            }
            if (w != oct) {
                float v = poll_pipelined(
                    &stateTag[((size_t)1 * BNUM + b) * 512 + e], want);
                stt[1][w][l] = v;
            }
            __syncthreads();
        }
        // ============ odd sub-step: step s+1, par 1 -> fills stt[0] ========
        {
            const int so = s + 1;
            const unsigned want = (unsigned)(so + 1);
            if (isPub) {
                size_t sp1 = (size_t)((so + 1) & (SLEN - 1));  // wraps at end
                gA  = pg [sp1 * 512 + o];
                cdA = pcd[sp1 * 512 + o];
                cA  = pc [sp1 * 256 + (o >> 1)];
                snA = psn[sp1 * 256 + (o >> 1)];
            }
            float t;
            DOT64(wt, &stt[1][kseg][0], t)
            t += __shfl_xor(t, 1);
            t += __shfl_xor(t, 2);
            t += __shfl_xor(t, 4);
            t += btv;
            float tp = __shfl_xor(t, 8);

            if (isPub) {
                float rot = (rl & 1) ? fmaf(tp, snB, t * cB)
                                     : fmaf(t, cB, -(tp * snB));
                float nxt = fmaf(gB, rot, (1.f - gB) * cdB);
                if (so + 1 < SLEN) {   // tag SLEN is never polled
                    uint2 u; u.x = __float_as_uint(nxt); u.y = want;
                    st_u64_sc1(&stateTag[((size_t)0 * BNUM + b) * 512 + o], u);
                }
                stt[0][oct][w * 8 + rl] = nxt;
                stb[(size_t)so * 512 + o] = nxt;
                if (so == SLEN - 1) finalOut[b * 512 + o] = nxt;
            }
            if (w != oct && so + 1 < SLEN) {
                float v = poll_pipelined(
                    &stateTag[((size_t)0 * BNUM + b) * 512 + e], want);
                stt[0][w][l] = v;
            }
            __syncthreads();
        }
    }
}

// ---------------------------------------------------------------------------
// Kernel C: emitted = og * (states @ Wo^T + bo) via bf16 MFMA (round-10,
// proven). og staged in d_out by kernel A; read then overwritten.
// ---------------------------------------------------------------------------
__global__ __launch_bounds__(256) void emit_kernel(
    const float* __restrict__ states, const float* __restrict__ Wo,
    const float* __restrict__ bo, float* __restrict__ out)
{
    __shared__ unsigned short As[128 * 40];
    __shared__ unsigned short Bs[128 * 40];

    const int bn = blockIdx.x * 128;
    const int bm = blockIdx.y * 128;

    const int tid  = threadIdx.x;
    const int lane = tid & 63, wv = tid >> 6;
    const int wm = wv >> 1, wn = wv & 1;
    const int lr  = lane & 15;
    const int lkb = (lane >> 4) * 8;

    f32x4 acc[4][4];
    #pragma unroll
    for (int i = 0; i < 4; ++i)
        #pragma unroll
        for (int j = 0; j < 4; ++j)
            acc[i][j] = (f32x4){0.f, 0.f, 0.f, 0.f};

    const int r = tid >> 1, h = tid & 1;
    const float* aSrc = states + (size_t)(bm + r) * DDIM + h * 16;
    const float* bSrc = Wo + (size_t)(bn + r) * DDIM + h * 16;
    unsigned short* aDst = &As[r * 40 + h * 16];
    unsigned short* bDst = &Bs[r * 40 + h * 16];

    for (int kt = 0; kt < 16; ++kt) {
        {
            float4 fa0 = *(const float4*)(aSrc + 0);
            float4 fa1 = *(const float4*)(aSrc + 4);
            float4 fa2 = *(const float4*)(aSrc + 8);
            float4 fa3 = *(const float4*)(aSrc + 12);
            union { unsigned short u[8]; s16x8 v; } pa0, pa1;
            pa0.u[0]=f2bf(fa0.x); pa0.u[1]=f2bf(fa0.y); pa0.u[2]=f2bf(fa0.z); pa0.u[3]=f2bf(fa0.w);
            pa0.u[4]=f2bf(fa1.x); pa0.u[5]=f2bf(fa1.y); pa0.u[6]=f2bf(fa1.z); pa0.u[7]=f2bf(fa1.w);
            pa1.u[0]=f2bf(fa2.x); pa1.u[1]=f2bf(fa2.y); pa1.u[2]=f2bf(fa2.z); pa1.u[3]=f2bf(fa2.w);
            pa1.u[4]=f2bf(fa3.x); pa1.u[5]=f2bf(fa3.y); pa1.u[6]=f2bf(fa3.z); pa1.u[7]=f2bf(fa3.w);
            *(s16x8*)(aDst + 0) = pa0.v;
            *(s16x8*)(aDst + 8) = pa1.v;

            float4 fb0 = *(const float4*)(bSrc + 0);
            float4 fb1 = *(const float4*)(bSrc + 4);
            float4 fb2 = *(const float4*)(bSrc + 8);
            float4 fb3 = *(const float4*)(bSrc + 12);
            union { unsigned short u[8]; s16x8 v; } pb0, pb1;
            pb0.u[0]=f2bf(fb0.x); pb0.u[1]=f2bf(fb0.y); pb0.u[2]=f2bf(fb0.z); pb0.u[3]=f2bf(fb0.w);
            pb0.u[4]=f2bf(fb1.x); pb0.u[5]=f2bf(fb1.y); pb0.u[6]=f2bf(fb1.z); pb0.u[7]=f2bf(fb1.w);
            pb1.u[0]=f2bf(fb2.x); pb1.u[1]=f2bf(fb2.y); pb1.u[2]=f2bf(fb2.z); pb1.u[3]=f2bf(fb2.w);
            pb1.u[4]=f2bf(fb3.x); pb1.u[5]=f2bf(fb3.y); pb1.u[6]=f2bf(fb3.z); pb1.u[7]=f2bf(fb3.w);
            *(s16x8*)(bDst + 0) = pb0.v;
            *(s16x8*)(bDst + 8) = pb1.v;

            aSrc += 32; bSrc += 32;
        }
        __syncthreads();

        s16x8 af[4], bf[4];
        #pragma unroll
        for (int i = 0; i < 4; ++i)
            af[i] = *(const s16x8*)&As[(wm * 64 + i * 16 + lr) * 40 + lkb];
        #pragma unroll
        for (int j = 0; j < 4; ++j)
            bf[j] = *(const s16x8*)&Bs[(wn * 64 + j * 16 + lr) * 40 + lkb];
        #pragma unroll
        for (int i = 0; i < 4; ++i)
            #pragma unroll
            for (int j = 0; j < 4; ++j)
                acc[i][j] = __builtin_amdgcn_mfma_f32_16x16x32_bf16(
                    af[i], bf[j], acc[i][j], 0, 0, 0);
        __syncthreads();
    }

    const int orow = (lane >> 4) * 4;
    #pragma unroll
    for (int i = 0; i < 4; ++i) {
        #pragma unroll
        for (int j = 0; j < 4; ++j) {
            #pragma unroll
            for (int v = 0; v < 4; ++v) {
                int m = bm + wm * 64 + i * 16 + orow + v;
                int n = bn + wn * 64 + j * 16 + lr;
                size_t idx = (size_t)m * 512 + n;
                float og = out[idx];
                out[idx] = og * (acc[i][j][v] + bo[n]);
            }
        }
    }
}

// ---------------------------------------------------------------------------
extern "C" void kernel_launch(void* const* d_in, const int* in_sizes, int n_in,
                              void* d_out, int out_size, void* d_ws, size_t ws_size,
                              hipStream_t stream)
{
    const float* x  = (const float*)d_in[0];
    const float* Wu = (const float*)d_in[1];
    const float* bu = (const float*)d_in[2];
    const float* Wt = (const float*)d_in[3];
    const float* bt = (const float*)d_in[4];
    const float* Wa = (const float*)d_in[5];
    const float* ba = (const float*)d_in[6];
    const float* Wc = (const float*)d_in[7];
    const float* bc = (const float*)d_in[8];
    const float* Wg = (const float*)d_in[9];
    const float* bg = (const float*)d_in[10];
    const float* Wo = (const float*)d_in[11];
    const float* bo = (const float*)d_in[12];
    float* out = (float*)d_out;

    // workspace layout (floats)
    float* wsf    = (float*)d_ws;
    float* gbuf   = wsf;                               // 16384*512
    float* cosb   = gbuf   + (size_t)MTOT * 512;       // 16384*256
    float* sinb   = cosb   + (size_t)MTOT * 256;       // 16384*256
    float* cdbuf  = sinb   + (size_t)MTOT * 256;       // 16384*512
    float* states = cdbuf  + (size_t)MTOT * 512;       // 16384*512
    uint2* stateTag = (uint2*)(states + (size_t)MTOT * 512); // 2*8*512 uint2

    clear_tags_kernel<<<16, 512, 0, stream>>>(stateTag);

    precompute_kernel<<<dim3(14, 128), 256, 0, stream>>>(
        x, Wu, bu, Wa, ba, Wc, bc, Wg, bg,
        gbuf, cosb, sinb, cdbuf, out /* og staged in emitted region */);

    scan_kernel<<<64, 512, 0, stream>>>(
        Wt, bt, gbuf, cosb, sinb, cdbuf,
        states, stateTag, out + (size_t)MTOT * 512);

    emit_kernel<<<dim3(4, 128), 256, 0, stream>>>(states, Wo, bo, out);
}

// Round 19
// 3084.334 us; speedup vs baseline: 1.3807x; 1.3807x over previous
//
#include <hip/hip_runtime.h>
#include <hip/hip_bf16.h>
#include <math.h>

#define SLEN 2048
#define DDIM 512
#define BNUM 8
#define MTOT (BNUM * SLEN)   // 16384

typedef float f32x4 __attribute__((ext_vector_type(4)));
typedef short s16x8 __attribute__((ext_vector_type(8)));   // 8 bf16 (4 VGPRs)

// fp32 -> bf16 (RNE) as raw ushort
__device__ __forceinline__ unsigned short f2bf(float f) {
    unsigned u = __float_as_uint(f);
    u += 0x7FFFu + ((u >> 16) & 1u);
    return (unsigned short)(u >> 16);
}

// ---------------------------------------------------------------------------
// Device-scope (sc1) 8-byte access helpers. sc1 = device scope, the
// narrowest scope coherent across CUs on different SEs/XCDs (r8: sc0 = SE
// scope fails cross-CU). All readers/writers of the tag buffer use this one
// path (r3 lesson). r13-r18 established: L2-atomic polls, batch pairing,
// post-poll gate reorder, and 4-deep pipelined polls ALL regress vs this
// structure — the scan sits at its ~2-LLC-RT/step latency floor.
// ---------------------------------------------------------------------------
__device__ __forceinline__ void st_u64_dev(uint2* p, uint2 v) {
    asm volatile("global_store_dwordx2 %0, %1, off sc1"
                 :: "v"(p), "v"(v) : "memory");
}
__device__ __forceinline__ uint2 ld_u64_dev(const uint2* p) {
    uint2 v;
    asm volatile("global_load_dwordx2 %0, %1, off sc1\n\ts_waitcnt vmcnt(0)"
                 : "=v"(v) : "v"(p) : "memory");
    return v;
}

// ---------------------------------------------------------------------------
// Kernel 0: clear tag buffer through the SAME sc1 path the scan uses.
// ---------------------------------------------------------------------------
__global__ __launch_bounds__(512) void clear_tags_kernel(uint2* stateTag)
{
    int i = blockIdx.x * 512 + threadIdx.x;
    uint2 z; z.x = 0u; z.y = 0u;
    st_u64_dev(&stateTag[i], z);
}

// ---------------------------------------------------------------------------
// Kernel A: fused precompute GEMM via bf16 MFMA (round-10, proven).
// ---------------------------------------------------------------------------
__global__ __launch_bounds__(256) void precompute_kernel(
    const float* __restrict__ x,
    const float* __restrict__ Wu, const float* __restrict__ bu,
    const float* __restrict__ Wa, const float* __restrict__ ba,
    const float* __restrict__ Wc, const float* __restrict__ bc,
    const float* __restrict__ Wg, const float* __restrict__ bg,
    float* __restrict__ gbuf, float* __restrict__ cosb,
    float* __restrict__ sinb, float* __restrict__ cdbuf,
    float* __restrict__ ogout)
{
    __shared__ unsigned short As[128 * 40];
    __shared__ unsigned short Bs[128 * 40];

    const int bn = blockIdx.x * 128;      // 0..1791 in steps of 128
    const int bm = blockIdx.y * 128;      // 0..16383

    const float* W; const float* bias; int mode; int dcol;
    if (bn < 512)       { W = Wu; bias = bu; mode = 0; dcol = bn; }
    else if (bn < 768)  { W = Wa; bias = ba; mode = 1; dcol = bn - 512; }
    else if (bn < 1280) { W = Wc; bias = bc; mode = 2; dcol = bn - 768; }
    else                { W = Wg; bias = bg; mode = 3; dcol = bn - 1280; }

    const int tid  = threadIdx.x;
    const int lane = tid & 63, wv = tid >> 6;
    const int wm = wv >> 1, wn = wv & 1;
    const int lr  = lane & 15;
    const int lkb = (lane >> 4) * 8;      // ushort offset of the 8-k group

    f32x4 acc[4][4];
    #pragma unroll
    for (int i = 0; i < 4; ++i)
        #pragma unroll
        for (int j = 0; j < 4; ++j)
            acc[i][j] = (f32x4){0.f, 0.f, 0.f, 0.f};

    const int r = tid >> 1, h = tid & 1;  // staging: row, k-half
    const float* aSrc = x + (size_t)(bm + r) * DDIM + h * 16;
    const float* bSrc = W + (size_t)(dcol + r) * DDIM + h * 16;
    unsigned short* aDst = &As[r * 40 + h * 16];
    unsigned short* bDst = &Bs[r * 40 + h * 16];

    for (int kt = 0; kt < 16; ++kt) {
        {
            float4 fa0 = *(const float4*)(aSrc + 0);
            float4 fa1 = *(const float4*)(aSrc + 4);
            float4 fa2 = *(const float4*)(aSrc + 8);
            float4 fa3 = *(const float4*)(aSrc + 12);
            union { unsigned short u[8]; s16x8 v; } pa0, pa1;
            pa0.u[0]=f2bf(fa0.x); pa0.u[1]=f2bf(fa0.y); pa0.u[2]=f2bf(fa0.z); pa0.u[3]=f2bf(fa0.w);
            pa0.u[4]=f2bf(fa1.x); pa0.u[5]=f2bf(fa1.y); pa0.u[6]=f2bf(fa1.z); pa0.u[7]=f2bf(fa1.w);
            pa1.u[0]=f2bf(fa2.x); pa1.u[1]=f2bf(fa2.y); pa1.u[2]=f2bf(fa2.z); pa1.u[3]=f2bf(fa2.w);
            pa1.u[4]=f2bf(fa3.x); pa1.u[5]=f2bf(fa3.y); pa1.u[6]=f2bf(fa3.z); pa1.u[7]=f2bf(fa3.w);
            *(s16x8*)(aDst + 0) = pa0.v;
            *(s16x8*)(aDst + 8) = pa1.v;

            float4 fb0 = *(const float4*)(bSrc + 0);
            float4 fb1 = *(const float4*)(bSrc + 4);
            float4 fb2 = *(const float4*)(bSrc + 8);
            float4 fb3 = *(const float4*)(bSrc + 12);
            union { unsigned short u[8]; s16x8 v; } pb0, pb1;
            pb0.u[0]=f2bf(fb0.x); pb0.u[1]=f2bf(fb0.y); pb0.u[2]=f2bf(fb0.z); pb0.u[3]=f2bf(fb0.w);
            pb0.u[4]=f2bf(fb1.x); pb0.u[5]=f2bf(fb1.y); pb0.u[6]=f2bf(fb1.z); pb0.u[7]=f2bf(fb1.w);
            pb1.u[0]=f2bf(fb2.x); pb1.u[1]=f2bf(fb2.y); pb1.u[2]=f2bf(fb2.z); pb1.u[3]=f2bf(fb2.w);
            pb1.u[4]=f2bf(fb3.x); pb1.u[5]=f2bf(fb3.y); pb1.u[6]=f2bf(fb3.z); pb1.u[7]=f2bf(fb3.w);
            *(s16x8*)(bDst + 0) = pb0.v;
            *(s16x8*)(bDst + 8) = pb1.v;

            aSrc += 32; bSrc += 32;
        }
        __syncthreads();

        s16x8 af[4], bf[4];
        #pragma unroll
        for (int i = 0; i < 4; ++i)
            af[i] = *(const s16x8*)&As[(wm * 64 + i * 16 + lr) * 40 + lkb];
        #pragma unroll
        for (int j = 0; j < 4; ++j)
            bf[j] = *(const s16x8*)&Bs[(wn * 64 + j * 16 + lr) * 40 + lkb];
        #pragma unroll
        for (int i = 0; i < 4; ++i)
            #pragma unroll
            for (int j = 0; j < 4; ++j)
                acc[i][j] = __builtin_amdgcn_mfma_f32_16x16x32_bf16(
                    af[i], bf[j], acc[i][j], 0, 0, 0);
        __syncthreads();
    }

    // ---- epilogue: bias + activation ----
    const int orow = (lane >> 4) * 4;
    #pragma unroll
    for (int i = 0; i < 4; ++i) {
        #pragma unroll
        for (int j = 0; j < 4; ++j) {
            #pragma unroll
            for (int v = 0; v < 4; ++v) {
                int m  = bm + wm * 64 + i * 16 + orow + v;
                int nc = dcol + wn * 64 + j * 16 + lr;
                float val = acc[i][j][v] + bias[nc];
                if (mode == 0) {
                    gbuf[(size_t)m * 512 + nc] = 1.f / (1.f + expf(-val));
                } else if (mode == 1) {
                    cosb[(size_t)m * 256 + nc] = cosf(val);
                    sinb[(size_t)m * 256 + nc] = sinf(val);
                } else if (mode == 2) {
                    cdbuf[(size_t)m * 512 + nc] = tanhf(val);
                } else {
                    ogout[(size_t)m * 512 + nc] = 1.f / (1.f + expf(-val));
                }
            }
        }
    }
}

// ---------------------------------------------------------------------------
// Kernel B: sequential scan, round-11 configuration (best measured:
// 1.29 us/step; rounds 13-18 variations all regressed). 64 WGs x 512 thr:
// b = wg&7, oct = wg>>3 owns rows [oct*64, +64). Lane (wave w, lane l):
// row o = oct*64 + w*8 + (l>>3), k-segment (l&7)*64 -> 64 fp32 weights in
// VGPR/AGPR (64/thread = the residency budget). Reduce = shfl_xor(1,2,4)
// + shfl_xor(8) for the rotation partner. kseg==0 lanes publish; wave
// w != oct polls segment w. Parity double-buffered LDS state -> ONE
// __syncthreads per step. sc1 generation-tagged double buffer (tag = s+1).
// Publisher-lane gate loads issue pre-poll: the poll's vmcnt(0) absorbs
// their drain inside the detect window (r17 proved post-poll is worse).
// ---------------------------------------------------------------------------
__global__ __launch_bounds__(512, 2) void scan_kernel(
    const float* __restrict__ Wt, const float* __restrict__ bt,
    const float* __restrict__ gbuf, const float* __restrict__ cosb,
    const float* __restrict__ sinb, const float* __restrict__ cdbuf,
    float* __restrict__ states, uint2* stateTag,
    float* __restrict__ finalOut)
{
    const int wg = blockIdx.x;
    const int b = wg & 7, oct = wg >> 3;
    const int tid = threadIdx.x;
    const int w = tid >> 6;          // wave index
    const int l = tid & 63;
    const int kseg = l & 7;          // k-segment of this lane's 64-wide slice
    const int rl = l >> 3;           // row within the wave's 8-row group
    const int o = oct * 64 + w * 8 + rl;   // row this lane computes
    const int e = w * 64 + l;        // state element wave w polls (w != oct)
    const bool isPub = (kseg == 0);

    __shared__ float stt[2][8][68];  // [parity][segment][element], padded

    // ---- register/AGPR-resident weight slice: Wt[o][kseg*64 .. +64) ----
    const float* wrow = Wt + (size_t)o * DDIM + kseg * 64;
    f32x4 w0  = *(const f32x4*)(wrow +  0);
    f32x4 w1  = *(const f32x4*)(wrow +  4);
    f32x4 w2  = *(const f32x4*)(wrow +  8);
    f32x4 w3  = *(const f32x4*)(wrow + 12);
    f32x4 w4  = *(const f32x4*)(wrow + 16);
    f32x4 w5  = *(const f32x4*)(wrow + 20);
    f32x4 w6  = *(const f32x4*)(wrow + 24);
    f32x4 w7  = *(const f32x4*)(wrow + 28);
    f32x4 w8  = *(const f32x4*)(wrow + 32);
    f32x4 w9  = *(const f32x4*)(wrow + 36);
    f32x4 w10 = *(const f32x4*)(wrow + 40);
    f32x4 w11 = *(const f32x4*)(wrow + 44);
    f32x4 w12 = *(const f32x4*)(wrow + 48);
    f32x4 w13 = *(const f32x4*)(wrow + 52);
    f32x4 w14 = *(const f32x4*)(wrow + 56);
    f32x4 w15 = *(const f32x4*)(wrow + 60);
    asm volatile("" : "+v"(w0), "+v"(w1), "+v"(w2),  "+v"(w3),
                      "+v"(w4), "+v"(w5), "+v"(w6),  "+v"(w7),
                      "+v"(w8), "+v"(w9), "+v"(w10), "+v"(w11),
                      "+v"(w12), "+v"(w13), "+v"(w14), "+v"(w15));

    const float btv = bt[o];

    const float* pg  = gbuf  + (size_t)b * SLEN * 512;
    const float* pcd = cdbuf + (size_t)b * SLEN * 512;
    const float* pc  = cosb  + (size_t)b * SLEN * 256;
    const float* psn = sinb  + (size_t)b * SLEN * 256;
    float* stb = states + (size_t)b * SLEN * 512;

    // init S_0 = 0 in parity 0 (each wave writes its segment row)
    stt[0][w][l] = 0.f;

    // gate prologue (publishing lanes only; one row each)
    float gN = 0.f, cdN = 0.f, cN = 0.f, snN = 0.f;
    if (isPub) {
        gN  = pg [o];
        cdN = pcd[o];
        cN  = pc [o >> 1];
        snN = psn[o >> 1];
    }
    __syncthreads();

    for (int s = 0; s < SLEN; ++s) {
        const int par = s & 1;

        // ---- partial over k-segment (64 MACs; conflict-free broadcast) ----
        float p0 = 0.f, p1 = 0.f, p2 = 0.f, p3 = 0.f;
        const float* st = &stt[par][kseg][0];
        {
            f32x4 sv;
            #define MACV(WV, OFF) \
                sv = *(const f32x4*)(st + OFF); \
                p0 = fmaf(WV.x, sv.x, p0); \
                p1 = fmaf(WV.y, sv.y, p1); \
                p2 = fmaf(WV.z, sv.z, p2); \
                p3 = fmaf(WV.w, sv.w, p3);
            MACV(w0,  0)  MACV(w1,  4)  MACV(w2,  8)  MACV(w3,  12)
            MACV(w4,  16) MACV(w5,  20) MACV(w6,  24) MACV(w7,  28)
            MACV(w8,  32) MACV(w9,  36) MACV(w10, 40) MACV(w11, 44)
            MACV(w12, 48) MACV(w13, 52) MACV(w14, 56) MACV(w15, 60)
            #undef MACV
        }
        float t = (p0 + p1) + (p2 + p3);
        t += __shfl_xor(t, 1);
        t += __shfl_xor(t, 2);
        t += __shfl_xor(t, 4);     // all 8 lanes of the group hold the dot
        t += btv;
        float tp = __shfl_xor(t, 8);   // partner row's value (rl ^ 1)

        if (isPub) {
            // ---- rotate, gate, publish row o (tag store FIRST) ----
            float rot = (rl & 1) ? fmaf(tp, snN, t * cN)
                                 : fmaf(t, cN, -(tp * snN));
            float nxt = fmaf(gN, rot, (1.f - gN) * cdN);
            if (s + 1 < SLEN) {   // tag SLEN is never polled
                uint2 u; u.x = __float_as_uint(nxt); u.y = (unsigned)(s + 1);
                st_u64_dev(&stateTag[((size_t)((s + 1) & 1) * BNUM + b) * 512 + o], u);
            }
            stb[(size_t)s * 512 + o] = nxt;            // for emit kernel
            stt[par ^ 1][oct][w * 8 + rl] = nxt;       // own element, next step
            if (s == SLEN - 1) finalOut[b * 512 + o] = nxt;
            // prefetch next step's gates (wrap harmlessly at the end)
            int sp1 = (s + 1) & (SLEN - 1);
            gN  = pg [(size_t)sp1 * 512 + o];
            cdN = pcd[(size_t)sp1 * 512 + o];
            cN  = pc [(size_t)sp1 * 256 + (o >> 1)];
            snN = psn[(size_t)sp1 * 256 + (o >> 1)];
        }
        if (w != oct && s + 1 < SLEN) {
            // ---- poll segment w for step s+1, fill other parity ----
            const uint2* pp = &stateTag[((size_t)((s + 1) & 1) * BNUM + b) * 512 + e];
            uint2 u; int guard = 0;
            do { u = ld_u64_dev(pp); }
            while (u.y != (unsigned)(s + 1) && ++guard < (1 << 16));
            stt[par ^ 1][w][l] = __uint_as_float(u.x);
        }
        __syncthreads();   // stt[par^1] complete -> next step's compute
    }
}

// ---------------------------------------------------------------------------
// Kernel C: emitted = og * (states @ Wo^T + bo) via bf16 MFMA (round-10,
// proven). og staged in d_out by kernel A; read then overwritten.
// ---------------------------------------------------------------------------
__global__ __launch_bounds__(256) void emit_kernel(
    const float* __restrict__ states, const float* __restrict__ Wo,
    const float* __restrict__ bo, float* __restrict__ out)
{
    __shared__ unsigned short As[128 * 40];
    __shared__ unsigned short Bs[128 * 40];

    const int bn = blockIdx.x * 128;
    const int bm = blockIdx.y * 128;

    const int tid  = threadIdx.x;
    const int lane = tid & 63, wv = tid >> 6;
    const int wm = wv >> 1, wn = wv & 1;
    const int lr  = lane & 15;
    const int lkb = (lane >> 4) * 8;

    f32x4 acc[4][4];
    #pragma unroll
    for (int i = 0; i < 4; ++i)
        #pragma unroll
        for (int j = 0; j < 4; ++j)
            acc[i][j] = (f32x4){0.f, 0.f, 0.f, 0.f};

    const int r = tid >> 1, h = tid & 1;
    const float* aSrc = states + (size_t)(bm + r) * DDIM + h * 16;
    const float* bSrc = Wo + (size_t)(bn + r) * DDIM + h * 16;
    unsigned short* aDst = &As[r * 40 + h * 16];
    unsigned short* bDst = &Bs[r * 40 + h * 16];

    for (int kt = 0; kt < 16; ++kt) {
        {
            float4 fa0 = *(const float4*)(aSrc + 0);
            float4 fa1 = *(const float4*)(aSrc + 4);
            float4 fa2 = *(const float4*)(aSrc + 8);
            float4 fa3 = *(const float4*)(aSrc + 12);
            union { unsigned short u[8]; s16x8 v; } pa0, pa1;
            pa0.u[0]=f2bf(fa0.x); pa0.u[1]=f2bf(fa0.y); pa0.u[2]=f2bf(fa0.z); pa0.u[3]=f2bf(fa0.w);
            pa0.u[4]=f2bf(fa1.x); pa0.u[5]=f2bf(fa1.y); pa0.u[6]=f2bf(fa1.z); pa0.u[7]=f2bf(fa1.w);
            pa1.u[0]=f2bf(fa2.x); pa1.u[1]=f2bf(fa2.y); pa1.u[2]=f2bf(fa2.z); pa1.u[3]=f2bf(fa2.w);
            pa1.u[4]=f2bf(fa3.x); pa1.u[5]=f2bf(fa3.y); pa1.u[6]=f2bf(fa3.z); pa1.u[7]=f2bf(fa3.w);
            *(s16x8*)(aDst + 0) = pa0.v;
            *(s16x8*)(aDst + 8) = pa1.v;

            float4 fb0 = *(const float4*)(bSrc + 0);
            float4 fb1 = *(const float4*)(bSrc + 4);
            float4 fb2 = *(const float4*)(bSrc + 8);
            float4 fb3 = *(const float4*)(bSrc + 12);
            union { unsigned short u[8]; s16x8 v; } pb0, pb1;
            pb0.u[0]=f2bf(fb0.x); pb0.u[1]=f2bf(fb0.y); pb0.u[2]=f2bf(fb0.z); pb0.u[3]=f2bf(fb0.w);
            pb0.u[4]=f2bf(fb1.x); pb0.u[5]=f2bf(fb1.y); pb0.u[6]=f2bf(fb1.z); pb0.u[7]=f2bf(fb1.w);
            pb1.u[0]=f2bf(fb2.x); pb1.u[1]=f2bf(fb2.y); pb1.u[2]=f2bf(fb2.z); pb1.u[3]=f2bf(fb2.w);
            pb1.u[4]=f2bf(fb3.x); pb1.u[5]=f2bf(fb3.y); pb1.u[6]=f2bf(fb3.z); pb1.u[7]=f2bf(fb3.w);
            *(s16x8*)(bDst + 0) = pb0.v;
            *(s16x8*)(bDst + 8) = pb1.v;

            aSrc += 32; bSrc += 32;
        }
        __syncthreads();

        s16x8 af[4], bf[4];
        #pragma unroll
        for (int i = 0; i < 4; ++i)
            af[i] = *(const s16x8*)&As[(wm * 64 + i * 16 + lr) * 40 + lkb];
        #pragma unroll
        for (int j = 0; j < 4; ++j)
            bf[j] = *(const s16x8*)&Bs[(wn * 64 + j * 16 + lr) * 40 + lkb];
        #pragma unroll
        for (int i = 0; i < 4; ++i)
            #pragma unroll
            for (int j = 0; j < 4; ++j)
                acc[i][j] = __builtin_amdgcn_mfma_f32_16x16x32_bf16(
                    af[i], bf[j], acc[i][j], 0, 0, 0);
        __syncthreads();
    }

    const int orow = (lane >> 4) * 4;
    #pragma unroll
    for (int i = 0; i < 4; ++i) {
        #pragma unroll
        for (int j = 0; j < 4; ++j) {
            #pragma unroll
            for (int v = 0; v < 4; ++v) {
                int m = bm + wm * 64 + i * 16 + orow + v;
                int n = bn + wn * 64 + j * 16 + lr;
                size_t idx = (size_t)m * 512 + n;
                float og = out[idx];
                out[idx] = og * (acc[i][j][v] + bo[n]);
            }
        }
    }
}

// ---------------------------------------------------------------------------
extern "C" void kernel_launch(void* const* d_in, const int* in_sizes, int n_in,
                              void* d_out, int out_size, void* d_ws, size_t ws_size,
                              hipStream_t stream)
{
    const float* x  = (const float*)d_in[0];
    const float* Wu = (const float*)d_in[1];
    const float* bu = (const float*)d_in[2];
    const float* Wt = (const float*)d_in[3];
    const float* bt = (const float*)d_in[4];
    const float* Wa = (const float*)d_in[5];
    const float* ba = (const float*)d_in[6];
    const float* Wc = (const float*)d_in[7];
    const float* bc = (const float*)d_in[8];
    const float* Wg = (const float*)d_in[9];
    const float* bg = (const float*)d_in[10];
    const float* Wo = (const float*)d_in[11];
    const float* bo = (const float*)d_in[12];
    float* out = (float*)d_out;

    // workspace layout (floats)
    float* wsf    = (float*)d_ws;
    float* gbuf   = wsf;                               // 16384*512
    float* cosb   = gbuf   + (size_t)MTOT * 512;       // 16384*256
    float* sinb   = cosb   + (size_t)MTOT * 256;       // 16384*256
    float* cdbuf  = sinb   + (size_t)MTOT * 256;       // 16384*512
    float* states = cdbuf  + (size_t)MTOT * 512;       // 16384*512
    uint2* stateTag = (uint2*)(states + (size_t)MTOT * 512); // 2*8*512 uint2

    clear_tags_kernel<<<16, 512, 0, stream>>>(stateTag);

    precompute_kernel<<<dim3(14, 128), 256, 0, stream>>>(
        x, Wu, bu, Wa, ba, Wc, bc, Wg, bg,
        gbuf, cosb, sinb, cdbuf, out /* og staged in emitted region */);

    scan_kernel<<<64, 512, 0, stream>>>(
        Wt, bt, gbuf, cosb, sinb, cdbuf,
        states, stateTag, out + (size_t)MTOT * 512);

    emit_kernel<<<dim3(4, 128), 256, 0, stream>>>(states, Wo, bo, out);
}